// Round 1
// baseline (407.886 us; speedup 1.0000x reference)
//
#include <hip/hip_runtime.h>

#define F 128
#define NG 512

// ---------------- CSR build ----------------

__global__ void deg_kernel(const int* __restrict__ src, int* __restrict__ deg, int E) {
    int e = blockIdx.x * blockDim.x + threadIdx.x;
    if (e < E) atomicAdd(&deg[src[e]], 1);
}

__global__ __launch_bounds__(1024) void scan_kernel(const int* __restrict__ deg,
                                                    int* __restrict__ rowptr,
                                                    int* __restrict__ cursor, int N) {
    // N == 32768 == 1024 * 32
    __shared__ int sums[1024];
    int tid = threadIdx.x;
    int base = tid * 32;
    int local[32];
    int s = 0;
    #pragma unroll
    for (int i = 0; i < 32; ++i) { local[i] = s; s += deg[base + i]; }
    sums[tid] = s;
    __syncthreads();
    for (int off = 1; off < 1024; off <<= 1) {
        int v = (tid >= off) ? sums[tid - off] : 0;
        __syncthreads();
        sums[tid] += v;
        __syncthreads();
    }
    int bs = (tid == 0) ? 0 : sums[tid - 1];
    #pragma unroll
    for (int i = 0; i < 32; ++i) {
        int v = bs + local[i];
        rowptr[base + i] = v;
        cursor[base + i] = v;
    }
    if (tid == 1023) rowptr[N] = sums[1023];
}

__global__ void scatter_kernel(const int* __restrict__ src, const int* __restrict__ dst,
                               int* __restrict__ cursor, int* __restrict__ col, int E) {
    int e = blockIdx.x * blockDim.x + threadIdx.x;
    if (e < E) {
        int p = atomicAdd(&cursor[src[e]], 1);
        col[p] = dst[e];
    }
}

// ---------------- SpMM: out[i] = alpha * sum_nbr X[col] + (1-alpha) * X[i] ----------------

__global__ __launch_bounds__(256) void spmm_kernel(const float* __restrict__ X,
                                                   float* __restrict__ out,
                                                   const int* __restrict__ rowptr,
                                                   const int* __restrict__ col,
                                                   const float* __restrict__ alphap, int N) {
    int w = (int)((blockIdx.x * blockDim.x + threadIdx.x) >> 6);
    int lane = threadIdx.x & 63;
    if (w >= N) return;
    float alpha = *alphap;
    int s = rowptr[w], e = rowptr[w + 1];
    float2 acc = make_float2(0.f, 0.f);
    const float2* X2 = (const float2*)X;
    for (int p = s; p < e; ++p) {
        int j = col[p];
        float2 v = X2[(size_t)j * 64 + lane];
        acc.x += v.x;
        acc.y += v.y;
    }
    float2 self = X2[(size_t)w * 64 + lane];
    float beta = 1.0f - alpha;
    float2 r;
    r.x = alpha * acc.x + beta * self.x;
    r.y = alpha * acc.y + beta * self.y;
    ((float2*)out)[(size_t)w * 64 + lane] = r;
}

// ---------------- fused conv GEMM: out = relu(A0@W[0] + A1@W[1] + A2@W[2] + b) ----------------
// tile: 64 rows x 128 cols per block (256 threads), acc[8][4] per thread.
// NOTE: `out` may alias A1 — each block only writes rows it has already fully consumed.

__global__ __launch_bounds__(256) void conv_gemm_kernel(
    const float* __restrict__ A0, const float* __restrict__ A1, const float* __restrict__ A2,
    const float* __restrict__ W,     // [3][128][128]  (k-major, g contiguous)
    const float* __restrict__ bias,  // [128]
    float* __restrict__ out, int N) {
    __shared__ float As[64 * F];
    int row0 = blockIdx.x * 64;
    int tid = threadIdx.x;
    int tx = tid & 31;   // cols tx*4 .. tx*4+3
    int ty = tid >> 5;   // rows ty*8 .. ty*8+7

    float acc[8][4];
    #pragma unroll
    for (int r = 0; r < 8; ++r)
        #pragma unroll
        for (int c = 0; c < 4; ++c) acc[r][c] = 0.f;

    const float* srcs[3] = {A0, A1, A2};
    for (int s = 0; s < 3; ++s) {
        __syncthreads();
        const float4* Ag = (const float4*)(srcs[s] + (size_t)row0 * F);
        float4* As4 = (float4*)As;
        #pragma unroll
        for (int idx = tid; idx < 64 * F / 4; idx += 256) As4[idx] = Ag[idx];
        __syncthreads();
        const float* Ws = W + (size_t)s * F * F;
        #pragma unroll 4
        for (int k = 0; k < F; ++k) {
            float4 wv = *(const float4*)&Ws[k * F + tx * 4];
            #pragma unroll
            for (int r = 0; r < 8; ++r) {
                float a = As[(ty * 8 + r) * F + k];
                acc[r][0] += a * wv.x;
                acc[r][1] += a * wv.y;
                acc[r][2] += a * wv.z;
                acc[r][3] += a * wv.w;
            }
        }
    }
    float4 bv = *(const float4*)&bias[tx * 4];
    #pragma unroll
    for (int r = 0; r < 8; ++r) {
        float4 o;
        o.x = fmaxf(acc[r][0] + bv.x, 0.f);
        o.y = fmaxf(acc[r][1] + bv.y, 0.f);
        o.z = fmaxf(acc[r][2] + bv.z, 0.f);
        o.w = fmaxf(acc[r][3] + bv.w, 0.f);
        *(float4*)&out[(size_t)(row0 + ty * 8 + r) * F + tx * 4] = o;
    }
}

// ---------------- max pool over nodes per graph ----------------

__global__ __launch_bounds__(512) void maxpool_kernel(const float* __restrict__ H,
                                                      float* __restrict__ pooled) {
    __shared__ float red[512];
    int b = blockIdx.x;
    int f = threadIdx.x & 127;
    int q = threadIdx.x >> 7;
    const float* base = H + (size_t)b * NG * F;
    float m = -3.402823466e38f;
    for (int i = q * (NG / 4); i < (q + 1) * (NG / 4); ++i)
        m = fmaxf(m, base[(size_t)i * F + f]);
    red[threadIdx.x] = m;
    __syncthreads();
    if (q == 0) {
        m = fmaxf(fmaxf(red[f], red[f + 128]), fmaxf(red[f + 256], red[f + 384]));
        pooled[(size_t)b * F + f] = m;
    }
}

// ---------------- output head: out = pooled @ Wout + bout ----------------

__global__ __launch_bounds__(64) void out_gemm_kernel(const float* __restrict__ pooled,
                                                      const float* __restrict__ Wout,
                                                      const float* __restrict__ bout,
                                                      float* __restrict__ out) {
    __shared__ float p[F];
    int b = blockIdx.x, g = threadIdx.x;
    p[g] = pooled[(size_t)b * F + g];
    p[g + 64] = pooled[(size_t)b * F + g + 64];
    __syncthreads();
    float acc = bout[g];
    #pragma unroll 8
    for (int k = 0; k < F; ++k) acc += p[k] * Wout[k * 64 + g];
    out[(size_t)b * 64 + g] = acc;
}

// ---------------- launch ----------------

extern "C" void kernel_launch(void* const* d_in, const int* in_sizes, int n_in,
                              void* d_out, int out_size, void* d_ws, size_t ws_size,
                              hipStream_t stream) {
    const float* X     = (const float*)d_in[0];
    const int*   ei    = (const int*)d_in[2];
    const float* W1    = (const float*)d_in[3];
    const float* b1    = (const float*)d_in[4];
    const float* W2    = (const float*)d_in[5];
    const float* b2    = (const float*)d_in[6];
    const float* Wout  = (const float*)d_in[7];
    const float* bout  = (const float*)d_in[8];
    const float* alpha = (const float*)d_in[9];

    const int N = in_sizes[0] / F;   // 32768
    const int E = in_sizes[2] / 2;   // 524288
    const int Bg = N / NG;           // 64

    const int* srcv = ei;
    const int* dstv = ei + E;

    char* ws = (char*)d_ws;
    size_t off = 0;
    auto alloc = [&](size_t bytes) {
        void* p = ws + off;
        off = (off + bytes + 15) & ~(size_t)15;
        return p;
    };
    int* rowptr   = (int*)alloc((size_t)(N + 1) * 4);
    int* deg      = (int*)alloc((size_t)N * 4);
    int* cursor   = (int*)alloc((size_t)N * 4);
    int* colv     = (int*)alloc((size_t)E * 4);
    float* buf1   = (float*)alloc((size_t)N * F * 4);
    float* buf2   = (float*)alloc((size_t)N * F * 4);
    float* buf3   = (float*)alloc((size_t)N * F * 4);
    float* pooled = (float*)alloc((size_t)Bg * F * 4);

    // CSR build
    hipMemsetAsync(deg, 0, (size_t)N * 4, stream);
    deg_kernel<<<(E + 255) / 256, 256, 0, stream>>>(srcv, deg, E);
    scan_kernel<<<1, 1024, 0, stream>>>(deg, rowptr, cursor, N);
    scatter_kernel<<<(E + 255) / 256, 256, 0, stream>>>(srcv, dstv, cursor, colv, E);

    const int spmm_blocks = N / 4;  // 4 waves (rows) per 256-thread block

    // layer 1
    spmm_kernel<<<spmm_blocks, 256, 0, stream>>>(X, buf1, rowptr, colv, alpha, N);     // S@X
    spmm_kernel<<<spmm_blocks, 256, 0, stream>>>(buf1, buf2, rowptr, colv, alpha, N);  // S^2@X
    conv_gemm_kernel<<<N / 64, 256, 0, stream>>>(X, buf1, buf2, W1, b1, buf3, N);      // H1

    // layer 2
    spmm_kernel<<<spmm_blocks, 256, 0, stream>>>(buf3, buf1, rowptr, colv, alpha, N);  // S@H1
    spmm_kernel<<<spmm_blocks, 256, 0, stream>>>(buf1, buf2, rowptr, colv, alpha, N);  // S^2@H1
    conv_gemm_kernel<<<N / 64, 256, 0, stream>>>(buf3, buf1, buf2, W2, b2, buf1, N);   // H2 (aliases A1, safe per-block)

    // head
    maxpool_kernel<<<Bg, 512, 0, stream>>>(buf1, pooled);
    out_gemm_kernel<<<Bg, 64, 0, stream>>>(pooled, Wout, bout, (float*)d_out);
}

// Round 2
// 351.874 us; speedup vs baseline: 1.1592x; 1.1592x over previous
//
#include <hip/hip_runtime.h>
#include <hip/hip_bf16.h>

#define F 128
#define NG 512

typedef __attribute__((ext_vector_type(8))) short s16x8;
typedef __attribute__((ext_vector_type(4))) float f32x4;

__device__ inline float bf2f(unsigned short u) {
    unsigned int x = ((unsigned int)u) << 16;
    return __builtin_bit_cast(float, x);
}
__device__ inline unsigned short f2bf(float f) {
    __hip_bfloat16 h = __float2bfloat16(f);
    return __builtin_bit_cast(unsigned short, h);
}

// ---------------- cast X f32 -> bf16 ----------------

__global__ __launch_bounds__(256) void cast_kernel(const float* __restrict__ X,
                                                   unsigned short* __restrict__ out, int n4) {
    int i = blockIdx.x * blockDim.x + threadIdx.x;
    if (i >= n4) return;
    float4 v = ((const float4*)X)[i];
    uint2 p;
    p.x = (unsigned int)f2bf(v.x) | ((unsigned int)f2bf(v.y) << 16);
    p.y = (unsigned int)f2bf(v.z) | ((unsigned int)f2bf(v.w) << 16);
    ((uint2*)out)[i] = p;
}

// ---------------- weight prep: W [384][128] f32 -> fragment-contiguous bf16 ----------------
// Wswz[ks][ct][lane][j] = bf16(W[ks*32 + (lane>>4)*8 + j][ct*16 + (lane&15)])

__global__ __launch_bounds__(256) void wprep_kernel(const float* __restrict__ W,
                                                    unsigned short* __restrict__ out) {
    int t = blockIdx.x * 256 + threadIdx.x;
    if (t >= 12 * 8 * 64 * 8) return;
    int j = t & 7;
    int lane = (t >> 3) & 63;
    int ct = (t >> 9) & 7;
    int ks = t >> 12;
    int k = ks * 32 + (lane >> 4) * 8 + j;
    int c = ct * 16 + (lane & 15);
    out[t] = f2bf(W[(size_t)k * F + c]);
}

// ---------------- CSR build ----------------

__global__ void deg_kernel(const int* __restrict__ src, int* __restrict__ deg, int E) {
    int e = blockIdx.x * blockDim.x + threadIdx.x;
    if (e < E) atomicAdd(&deg[src[e]], 1);
}

__global__ __launch_bounds__(1024) void scan_kernel(const int* __restrict__ deg,
                                                    int* __restrict__ rowptr,
                                                    int* __restrict__ cursor, int N) {
    __shared__ int sums[1024];
    int tid = threadIdx.x;
    int base = tid * 32;
    int local[32];
    int s = 0;
    #pragma unroll
    for (int i = 0; i < 32; ++i) { local[i] = s; s += deg[base + i]; }
    sums[tid] = s;
    __syncthreads();
    for (int off = 1; off < 1024; off <<= 1) {
        int v = (tid >= off) ? sums[tid - off] : 0;
        __syncthreads();
        sums[tid] += v;
        __syncthreads();
    }
    int bs = (tid == 0) ? 0 : sums[tid - 1];
    #pragma unroll
    for (int i = 0; i < 32; ++i) {
        int v = bs + local[i];
        rowptr[base + i] = v;
        cursor[base + i] = v;
    }
    if (tid == 1023) rowptr[N] = sums[1023];
}

__global__ void scatter_kernel(const int* __restrict__ src, const int* __restrict__ dst,
                               int* __restrict__ cursor, int* __restrict__ col, int E) {
    int e = blockIdx.x * blockDim.x + threadIdx.x;
    if (e < E) {
        int p = atomicAdd(&cursor[src[e]], 1);
        col[p] = dst[e];
    }
}

// ---------------- SpMM bf16: out[i] = alpha * sum_nbr X[col] + (1-alpha) * X[i] ----------------

__global__ __launch_bounds__(256) void spmm_bf16_kernel(const unsigned short* __restrict__ X,
                                                        unsigned short* __restrict__ out,
                                                        const int* __restrict__ rowptr,
                                                        const int* __restrict__ col,
                                                        const float* __restrict__ alphap, int N) {
    int w = (int)((blockIdx.x * blockDim.x + threadIdx.x) >> 6);
    int lane = threadIdx.x & 63;
    if (w >= N) return;
    float alpha = *alphap;
    int s = rowptr[w], e = rowptr[w + 1];
    const unsigned int* X2 = (const unsigned int*)X;
    float ax = 0.f, ay = 0.f;
    for (int p = s; p < e; ++p) {
        int j = col[p];
        unsigned int v = X2[(size_t)j * 64 + lane];
        ax += bf2f((unsigned short)(v & 0xffffu));
        ay += bf2f((unsigned short)(v >> 16));
    }
    unsigned int sv = X2[(size_t)w * 64 + lane];
    float beta = 1.0f - alpha;
    float rx = alpha * ax + beta * bf2f((unsigned short)(sv & 0xffffu));
    float ry = alpha * ay + beta * bf2f((unsigned short)(sv >> 16));
    ((unsigned int*)out)[(size_t)w * 64 + lane] =
        (unsigned int)f2bf(rx) | ((unsigned int)f2bf(ry) << 16);
}

// ---------------- conv via MFMA: out = relu(A0@W0 + A1@W1 + A2@W2 + b), all bf16 ----------------
// block: 512 threads = 8 waves; tile 128 rows x 128 cols; each wave 16 rows.
// A-fragments direct from global (no reuse); B-fragments from pre-shuffled Wswz (L1-hot).

__global__ __launch_bounds__(512) void conv_mfma_kernel(
    const unsigned short* __restrict__ A0, const unsigned short* __restrict__ A1,
    const unsigned short* __restrict__ A2, const unsigned short* __restrict__ Wswz,
    const float* __restrict__ bias, unsigned short* __restrict__ out) {
    __shared__ unsigned short smem[128 * F];
    int tid = threadIdx.x;
    int wave = tid >> 6;
    int lane = tid & 63;
    int arow = blockIdx.x * 128 + wave * 16 + (lane & 15);
    int asub = (lane >> 4) * 8;

    f32x4 acc[8];
    #pragma unroll
    for (int ct = 0; ct < 8; ++ct) acc[ct] = (f32x4){0.f, 0.f, 0.f, 0.f};

    const unsigned short* mats[3] = {A0, A1, A2};
    #pragma unroll
    for (int ks = 0; ks < 12; ++ks) {
        const unsigned short* Ab = mats[ks >> 2];
        int kk = ks & 3;
        s16x8 a = *(const s16x8*)(Ab + (size_t)arow * F + kk * 32 + asub);
        const unsigned short* wb = Wswz + ((size_t)ks * 8 * 64 + lane) * 8;
        #pragma unroll
        for (int ct = 0; ct < 8; ++ct) {
            s16x8 b = *(const s16x8*)(wb + (size_t)ct * 64 * 8);
            acc[ct] = __builtin_amdgcn_mfma_f32_16x16x32_bf16(a, b, acc[ct], 0, 0, 0);
        }
    }

    // epilogue: bias + relu -> bf16 via LDS, coalesced store
    int rloc = wave * 16 + ((lane >> 4) << 2);
    #pragma unroll
    for (int ct = 0; ct < 8; ++ct) {
        int c = ct * 16 + (lane & 15);
        float b = bias[c];
        #pragma unroll
        for (int r = 0; r < 4; ++r) {
            float v = fmaxf(acc[ct][r] + b, 0.f);
            smem[(size_t)(rloc + r) * F + c] = f2bf(v);
        }
    }
    __syncthreads();
    const uint4* s4 = (const uint4*)smem;
    uint4* o4 = (uint4*)(out + (size_t)blockIdx.x * 128 * F);
    #pragma unroll
    for (int i = tid; i < 128 * F / 8; i += 512) o4[i] = s4[i];
}

// ---------------- max pool over nodes per graph (bf16 in, f32 out) ----------------

__global__ __launch_bounds__(512) void maxpool_kernel(const unsigned short* __restrict__ H,
                                                      float* __restrict__ pooled) {
    __shared__ float redx[512];
    __shared__ float redy[512];
    int b = blockIdx.x;
    int c = threadIdx.x & 63;   // feature pair 2c, 2c+1
    int q = threadIdx.x >> 6;   // 8 row groups of 64
    const unsigned int* base = (const unsigned int*)(H + (size_t)b * NG * F);
    float mx = -3.402823466e38f, my = -3.402823466e38f;
    for (int i = q * 64; i < q * 64 + 64; ++i) {
        unsigned int v = base[(size_t)i * 64 + c];
        mx = fmaxf(mx, bf2f((unsigned short)(v & 0xffffu)));
        my = fmaxf(my, bf2f((unsigned short)(v >> 16)));
    }
    redx[threadIdx.x] = mx;
    redy[threadIdx.x] = my;
    __syncthreads();
    if (q == 0) {
        #pragma unroll
        for (int g = 1; g < 8; ++g) {
            mx = fmaxf(mx, redx[g * 64 + c]);
            my = fmaxf(my, redy[g * 64 + c]);
        }
        pooled[(size_t)b * F + 2 * c] = mx;
        pooled[(size_t)b * F + 2 * c + 1] = my;
    }
}

// ---------------- output head: out = pooled @ Wout + bout (f32) ----------------

__global__ __launch_bounds__(64) void out_gemm_kernel(const float* __restrict__ pooled,
                                                      const float* __restrict__ Wout,
                                                      const float* __restrict__ bout,
                                                      float* __restrict__ out) {
    __shared__ float p[F];
    int b = blockIdx.x, g = threadIdx.x;
    p[g] = pooled[(size_t)b * F + g];
    p[g + 64] = pooled[(size_t)b * F + g + 64];
    __syncthreads();
    float acc = bout[g];
    #pragma unroll 8
    for (int k = 0; k < F; ++k) acc += p[k] * Wout[k * 64 + g];
    out[(size_t)b * 64 + g] = acc;
}

// ---------------- launch ----------------

extern "C" void kernel_launch(void* const* d_in, const int* in_sizes, int n_in,
                              void* d_out, int out_size, void* d_ws, size_t ws_size,
                              hipStream_t stream) {
    const float* X     = (const float*)d_in[0];
    const int*   ei    = (const int*)d_in[2];
    const float* W1    = (const float*)d_in[3];
    const float* b1    = (const float*)d_in[4];
    const float* W2    = (const float*)d_in[5];
    const float* b2    = (const float*)d_in[6];
    const float* Wout  = (const float*)d_in[7];
    const float* bout  = (const float*)d_in[8];
    const float* alpha = (const float*)d_in[9];

    const int N = in_sizes[0] / F;   // 32768
    const int E = in_sizes[2] / 2;   // 524288
    const int Bg = N / NG;           // 64

    const int* srcv = ei;
    const int* dstv = ei + E;

    char* ws = (char*)d_ws;
    size_t off = 0;
    auto alloc = [&](size_t bytes) {
        void* p = ws + off;
        off = (off + bytes + 255) & ~(size_t)255;
        return p;
    };
    int* rowptr            = (int*)alloc((size_t)(N + 1) * 4);
    int* deg               = (int*)alloc((size_t)N * 4);
    int* cursor            = (int*)alloc((size_t)N * 4);
    int* colv              = (int*)alloc((size_t)E * 4);
    unsigned short* Xb     = (unsigned short*)alloc((size_t)N * F * 2);
    unsigned short* t1     = (unsigned short*)alloc((size_t)N * F * 2);
    unsigned short* t2     = (unsigned short*)alloc((size_t)N * F * 2);
    unsigned short* h1     = (unsigned short*)alloc((size_t)N * F * 2);
    unsigned short* h2     = (unsigned short*)alloc((size_t)N * F * 2);
    unsigned short* Wswz1  = (unsigned short*)alloc((size_t)3 * F * F * 2);
    unsigned short* Wswz2  = (unsigned short*)alloc((size_t)3 * F * F * 2);
    float* pooled          = (float*)alloc((size_t)Bg * F * 4);

    // prep: cast X, shuffle weights
    cast_kernel<<<(N * F / 4 + 255) / 256, 256, 0, stream>>>(X, Xb, N * F / 4);
    wprep_kernel<<<192, 256, 0, stream>>>(W1, Wswz1);
    wprep_kernel<<<192, 256, 0, stream>>>(W2, Wswz2);

    // CSR build
    hipMemsetAsync(deg, 0, (size_t)N * 4, stream);
    deg_kernel<<<(E + 255) / 256, 256, 0, stream>>>(srcv, deg, E);
    scan_kernel<<<1, 1024, 0, stream>>>(deg, rowptr, cursor, N);
    scatter_kernel<<<(E + 255) / 256, 256, 0, stream>>>(srcv, dstv, cursor, colv, E);

    const int spmm_blocks = N / 4;

    // layer 1
    spmm_bf16_kernel<<<spmm_blocks, 256, 0, stream>>>(Xb, t1, rowptr, colv, alpha, N);
    spmm_bf16_kernel<<<spmm_blocks, 256, 0, stream>>>(t1, t2, rowptr, colv, alpha, N);
    conv_mfma_kernel<<<N / 128, 512, 0, stream>>>(Xb, t1, t2, Wswz1, b1, h1);

    // layer 2
    spmm_bf16_kernel<<<spmm_blocks, 256, 0, stream>>>(h1, t1, rowptr, colv, alpha, N);
    spmm_bf16_kernel<<<spmm_blocks, 256, 0, stream>>>(t1, t2, rowptr, colv, alpha, N);
    conv_mfma_kernel<<<N / 128, 512, 0, stream>>>(h1, t1, t2, Wswz2, b2, h2);

    // head
    maxpool_kernel<<<Bg, 512, 0, stream>>>(h2, pooled);
    out_gemm_kernel<<<Bg, 64, 0, stream>>>(pooled, Wout, bout, (float*)d_out);
}

// Round 3
// 263.364 us; speedup vs baseline: 1.5488x; 1.3361x over previous
//
#include <hip/hip_runtime.h>
#include <hip/hip_bf16.h>

#define F 128
#define NG 512
#define SLICE 8   // dwords per feature slice = 16 bf16 features; 8 slices per row

typedef __attribute__((ext_vector_type(8))) short s16x8;
typedef __attribute__((ext_vector_type(4))) float f32x4;

__device__ inline float bf2f(unsigned short u) {
    unsigned int x = ((unsigned int)u) << 16;
    return __builtin_bit_cast(float, x);
}
__device__ inline unsigned short f2bf(float f) {
    __hip_bfloat16 h = __float2bfloat16(f);
    return __builtin_bit_cast(unsigned short, h);
}
__device__ inline float lo16(unsigned int v) { return bf2f((unsigned short)(v & 0xffffu)); }
__device__ inline float hi16(unsigned int v) { return bf2f((unsigned short)(v >> 16)); }
__device__ inline unsigned int pack16(float x, float y) {
    return (unsigned int)f2bf(x) | ((unsigned int)f2bf(y) << 16);
}

// ---------------- cast X f32 -> bf16 ----------------

__global__ __launch_bounds__(256) void cast_kernel(const float* __restrict__ X,
                                                   unsigned short* __restrict__ out, int n4) {
    int i = blockIdx.x * blockDim.x + threadIdx.x;
    if (i >= n4) return;
    float4 v = ((const float4*)X)[i];
    uint2 p;
    p.x = pack16(v.x, v.y);
    p.y = pack16(v.z, v.w);
    ((uint2*)out)[i] = p;
}

// ---------------- weight prep: W [384][128] f32 -> fragment-contiguous bf16 ----------------
// Wswz[ks][ct][lane][j] = bf16(W[ks*32 + (lane>>4)*8 + j][ct*16 + (lane&15)])

__global__ __launch_bounds__(256) void wprep_kernel(const float* __restrict__ W,
                                                    unsigned short* __restrict__ out) {
    int t = blockIdx.x * 256 + threadIdx.x;
    if (t >= 12 * 8 * 64 * 8) return;
    int j = t & 7;
    int lane = (t >> 3) & 63;
    int ct = (t >> 9) & 7;
    int ks = t >> 12;
    int k = ks * 32 + (lane >> 4) * 8 + j;
    int c = ct * 16 + (lane & 15);
    out[t] = f2bf(W[(size_t)k * F + c]);
}

// ---------------- CSR build ----------------

__global__ void deg_kernel(const int* __restrict__ src, int* __restrict__ deg, int E) {
    int e = blockIdx.x * blockDim.x + threadIdx.x;
    if (e < E) atomicAdd(&deg[src[e]], 1);
}

__global__ __launch_bounds__(1024) void scan_kernel(const int* __restrict__ deg,
                                                    int* __restrict__ rowptr,
                                                    int* __restrict__ cursor, int N) {
    __shared__ int sums[1024];
    int tid = threadIdx.x;
    int base = tid * 32;
    int local[32];
    int s = 0;
    #pragma unroll
    for (int i = 0; i < 32; ++i) { local[i] = s; s += deg[base + i]; }
    sums[tid] = s;
    __syncthreads();
    for (int off = 1; off < 1024; off <<= 1) {
        int v = (tid >= off) ? sums[tid - off] : 0;
        __syncthreads();
        sums[tid] += v;
        __syncthreads();
    }
    int bs = (tid == 0) ? 0 : sums[tid - 1];
    #pragma unroll
    for (int i = 0; i < 32; ++i) {
        int v = bs + local[i];
        rowptr[base + i] = v;
        cursor[base + i] = v;
    }
    if (tid == 1023) rowptr[N] = sums[1023];
}

__global__ void scatter_kernel(const int* __restrict__ src, const int* __restrict__ dst,
                               int* __restrict__ cursor, int* __restrict__ col, int E) {
    int e = blockIdx.x * blockDim.x + threadIdx.x;
    if (e < E) {
        int p = atomicAdd(&cursor[src[e]], 1);
        col[p] = dst[e];
    }
}

// ---------------- fused double SpMM per (graph, slice): t1 = S@X, t2 = S@t1 ----------------
// block: 512 threads = 8 waves; LDS bufA/bufB = 16 KB each (512 rows x 8 dwords).
// Each 8-lane group owns one row per pass; gathers from LDS.

__global__ __launch_bounds__(512) void spmm2_kernel(const unsigned short* __restrict__ Xin,
                                                    unsigned short* __restrict__ t1,
                                                    unsigned short* __restrict__ t2,
                                                    const int* __restrict__ rowptr,
                                                    const int* __restrict__ col,
                                                    const float* __restrict__ alphap) {
    __shared__ unsigned int bufA[NG * SLICE];
    __shared__ unsigned int bufB[NG * SLICE];
    const int g = blockIdx.x >> 3;
    const int q = blockIdx.x & 7;
    const int tid = threadIdx.x;
    const float alpha = *alphap;
    const float beta = 1.0f - alpha;

    const unsigned int* Xg = (const unsigned int*)Xin + (size_t)g * NG * 64 + q * SLICE;
    unsigned int* t1g = (unsigned int*)t1 + (size_t)g * NG * 64 + q * SLICE;
    unsigned int* t2g = (unsigned int*)t2 + (size_t)g * NG * 64 + q * SLICE;

    // stage X slice into bufA (1024 uint4 total, 2 per thread)
    #pragma unroll
    for (int u = tid; u < NG * SLICE / 4; u += 512) {
        int row = u >> 1;
        int part = u & 1;
        ((uint4*)bufA)[u] = *(const uint4*)(Xg + (size_t)row * 64 + part * 4);
    }

    const int wave = tid >> 6;
    const int lane = tid & 63;
    const int sub = lane >> 3;   // row within wave, 0..7
    const int fl = lane & 7;     // dword within slice
    const int G = g * NG;

    const unsigned int* src = bufA;
    unsigned int* outg = t1g;
    #pragma unroll
    for (int round = 0; round < 2; ++round) {
        __syncthreads();
        #pragma unroll
        for (int pass = 0; pass < NG / 64; ++pass) {
            int r = pass * 64 + wave * 8 + sub;
            int s = rowptr[G + r];
            int e = rowptr[G + r + 1];
            float ax = 0.f, ay = 0.f;
            int p = s;
            for (; p + 4 <= e; p += 4) {
                int j0 = col[p] & (NG - 1);
                int j1 = col[p + 1] & (NG - 1);
                int j2 = col[p + 2] & (NG - 1);
                int j3 = col[p + 3] & (NG - 1);
                unsigned int v0 = src[j0 * SLICE + fl];
                unsigned int v1 = src[j1 * SLICE + fl];
                unsigned int v2 = src[j2 * SLICE + fl];
                unsigned int v3 = src[j3 * SLICE + fl];
                ax += (lo16(v0) + lo16(v1)) + (lo16(v2) + lo16(v3));
                ay += (hi16(v0) + hi16(v1)) + (hi16(v2) + hi16(v3));
            }
            for (; p < e; ++p) {
                int j = col[p] & (NG - 1);
                unsigned int v = src[j * SLICE + fl];
                ax += lo16(v);
                ay += hi16(v);
            }
            unsigned int sv = src[r * SLICE + fl];
            unsigned int o = pack16(alpha * ax + beta * lo16(sv),
                                    alpha * ay + beta * hi16(sv));
            if (round == 0) bufB[r * SLICE + fl] = o;
            outg[(size_t)r * 64 + fl] = o;
        }
        src = bufB;
        outg = t2g;
    }
}

// ---------------- conv via MFMA: out = relu(A0@W0 + A1@W1 + A2@W2 + b), all bf16 ----------------

__global__ __launch_bounds__(512) void conv_mfma_kernel(
    const unsigned short* __restrict__ A0, const unsigned short* __restrict__ A1,
    const unsigned short* __restrict__ A2, const unsigned short* __restrict__ Wswz,
    const float* __restrict__ bias, unsigned short* __restrict__ out) {
    __shared__ unsigned short smem[128 * F];
    int tid = threadIdx.x;
    int wave = tid >> 6;
    int lane = tid & 63;
    int arow = blockIdx.x * 128 + wave * 16 + (lane & 15);
    int asub = (lane >> 4) * 8;

    f32x4 acc[8];
    #pragma unroll
    for (int ct = 0; ct < 8; ++ct) acc[ct] = (f32x4){0.f, 0.f, 0.f, 0.f};

    const unsigned short* mats[3] = {A0, A1, A2};
    #pragma unroll
    for (int ks = 0; ks < 12; ++ks) {
        const unsigned short* Ab = mats[ks >> 2];
        int kk = ks & 3;
        s16x8 a = *(const s16x8*)(Ab + (size_t)arow * F + kk * 32 + asub);
        const unsigned short* wb = Wswz + ((size_t)ks * 8 * 64 + lane) * 8;
        #pragma unroll
        for (int ct = 0; ct < 8; ++ct) {
            s16x8 b = *(const s16x8*)(wb + (size_t)ct * 64 * 8);
            acc[ct] = __builtin_amdgcn_mfma_f32_16x16x32_bf16(a, b, acc[ct], 0, 0, 0);
        }
    }

    int rloc = wave * 16 + ((lane >> 4) << 2);
    #pragma unroll
    for (int ct = 0; ct < 8; ++ct) {
        int c = ct * 16 + (lane & 15);
        float b = bias[c];
        #pragma unroll
        for (int r = 0; r < 4; ++r) {
            float v = fmaxf(acc[ct][r] + b, 0.f);
            smem[(size_t)(rloc + r) * F + c] = f2bf(v);
        }
    }
    __syncthreads();
    const uint4* s4 = (const uint4*)smem;
    uint4* o4 = (uint4*)(out + (size_t)blockIdx.x * 128 * F);
    #pragma unroll
    for (int i = tid; i < 128 * F / 8; i += 512) o4[i] = s4[i];
}

// ---------------- max pool over nodes per graph (bf16 in, f32 out) ----------------

__global__ __launch_bounds__(512) void maxpool_kernel(const unsigned short* __restrict__ H,
                                                      float* __restrict__ pooled) {
    __shared__ float redx[512];
    __shared__ float redy[512];
    int b = blockIdx.x;
    int c = threadIdx.x & 63;
    int q = threadIdx.x >> 6;
    const unsigned int* base = (const unsigned int*)(H + (size_t)b * NG * F);
    float mx = -3.402823466e38f, my = -3.402823466e38f;
    for (int i = q * 64; i < q * 64 + 64; ++i) {
        unsigned int v = base[(size_t)i * 64 + c];
        mx = fmaxf(mx, lo16(v));
        my = fmaxf(my, hi16(v));
    }
    redx[threadIdx.x] = mx;
    redy[threadIdx.x] = my;
    __syncthreads();
    if (q == 0) {
        #pragma unroll
        for (int gq = 1; gq < 8; ++gq) {
            mx = fmaxf(mx, redx[gq * 64 + c]);
            my = fmaxf(my, redy[gq * 64 + c]);
        }
        pooled[(size_t)b * F + 2 * c] = mx;
        pooled[(size_t)b * F + 2 * c + 1] = my;
    }
}

// ---------------- output head: out = pooled @ Wout + bout (f32) ----------------

__global__ __launch_bounds__(64) void out_gemm_kernel(const float* __restrict__ pooled,
                                                      const float* __restrict__ Wout,
                                                      const float* __restrict__ bout,
                                                      float* __restrict__ out) {
    __shared__ float p[F];
    int b = blockIdx.x, g = threadIdx.x;
    p[g] = pooled[(size_t)b * F + g];
    p[g + 64] = pooled[(size_t)b * F + g + 64];
    __syncthreads();
    float acc = bout[g];
    #pragma unroll 8
    for (int k = 0; k < F; ++k) acc += p[k] * Wout[k * 64 + g];
    out[(size_t)b * 64 + g] = acc;
}

// ---------------- launch ----------------

extern "C" void kernel_launch(void* const* d_in, const int* in_sizes, int n_in,
                              void* d_out, int out_size, void* d_ws, size_t ws_size,
                              hipStream_t stream) {
    const float* X     = (const float*)d_in[0];
    const int*   ei    = (const int*)d_in[2];
    const float* W1    = (const float*)d_in[3];
    const float* b1    = (const float*)d_in[4];
    const float* W2    = (const float*)d_in[5];
    const float* b2    = (const float*)d_in[6];
    const float* Wout  = (const float*)d_in[7];
    const float* bout  = (const float*)d_in[8];
    const float* alpha = (const float*)d_in[9];

    const int N = in_sizes[0] / F;   // 32768
    const int E = in_sizes[2] / 2;   // 524288
    const int Bg = N / NG;           // 64

    const int* srcv = ei;
    const int* dstv = ei + E;

    char* ws = (char*)d_ws;
    size_t off = 0;
    auto alloc = [&](size_t bytes) {
        void* p = ws + off;
        off = (off + bytes + 255) & ~(size_t)255;
        return p;
    };
    int* rowptr            = (int*)alloc((size_t)(N + 1) * 4);
    int* deg               = (int*)alloc((size_t)N * 4);
    int* cursor            = (int*)alloc((size_t)N * 4);
    int* colv              = (int*)alloc((size_t)E * 4);
    unsigned short* Xb     = (unsigned short*)alloc((size_t)N * F * 2);
    unsigned short* t1     = (unsigned short*)alloc((size_t)N * F * 2);
    unsigned short* t2     = (unsigned short*)alloc((size_t)N * F * 2);
    unsigned short* h1     = (unsigned short*)alloc((size_t)N * F * 2);
    unsigned short* h2     = (unsigned short*)alloc((size_t)N * F * 2);
    unsigned short* Wswz1  = (unsigned short*)alloc((size_t)3 * F * F * 2);
    unsigned short* Wswz2  = (unsigned short*)alloc((size_t)3 * F * F * 2);
    float* pooled          = (float*)alloc((size_t)Bg * F * 4);

    // prep: cast X, shuffle weights
    cast_kernel<<<(N * F / 4 + 255) / 256, 256, 0, stream>>>(X, Xb, N * F / 4);
    wprep_kernel<<<192, 256, 0, stream>>>(W1, Wswz1);
    wprep_kernel<<<192, 256, 0, stream>>>(W2, Wswz2);

    // CSR build
    hipMemsetAsync(deg, 0, (size_t)N * 4, stream);
    deg_kernel<<<(E + 255) / 256, 256, 0, stream>>>(srcv, deg, E);
    scan_kernel<<<1, 1024, 0, stream>>>(deg, rowptr, cursor, N);
    scatter_kernel<<<(E + 255) / 256, 256, 0, stream>>>(srcv, dstv, cursor, colv, E);

    // layer 1: t1 = S@X, t2 = S@t1 (fused), then conv
    spmm2_kernel<<<Bg * 8, 512, 0, stream>>>(Xb, t1, t2, rowptr, colv, alpha);
    conv_mfma_kernel<<<N / 128, 512, 0, stream>>>(Xb, t1, t2, Wswz1, b1, h1);

    // layer 2
    spmm2_kernel<<<Bg * 8, 512, 0, stream>>>(h1, t1, t2, rowptr, colv, alpha);
    conv_mfma_kernel<<<N / 128, 512, 0, stream>>>(h1, t1, t2, Wswz2, b2, h2);

    // head
    maxpool_kernel<<<Bg, 512, 0, stream>>>(h2, pooled);
    out_gemm_kernel<<<Bg, 64, 0, stream>>>(pooled, Wout, bout, (float*)d_out);
}